// Round 3
// baseline (605.116 us; speedup 1.0000x reference)
//
#include <hip/hip_runtime.h>
#include <hip/hip_bf16.h>

// ---------------------------------------------------------------------------
// BGE-M3 style scoring: dense (CLS cosine), sparse (scatter-max vocab dot),
// colbert (maxsim).  Shapes: q_hidden [8,128,1024], p_hidden [64,512,1024].
// Out = concat(dense[8,64], sparse[8,64], colbert[8,64]) fp32.
// ---------------------------------------------------------------------------

typedef __bf16 bf16x8 __attribute__((ext_vector_type(8)));
typedef float floatx4 __attribute__((ext_vector_type(4)));

#define TEMP 0.02f

__device__ __forceinline__ unsigned short f2bf(float f) {
    unsigned u = __float_as_uint(f);
    unsigned r = (u + 0x7FFFu + ((u >> 16) & 1u)) >> 16;  // RNE
    return (unsigned short)r;
}
__device__ __forceinline__ float bf2f(unsigned short h) {
    return __uint_as_float(((unsigned)h) << 16);
}
// order-preserving float<->uint encode for atomicMax on possibly-negative floats
__device__ __forceinline__ unsigned encf(float f) {
    unsigned u = __float_as_uint(f);
    return (u & 0x80000000u) ? ~u : (u | 0x80000000u);
}
__device__ __forceinline__ float decf(unsigned u) {
    return __uint_as_float((u & 0x80000000u) ? (u & 0x7FFFFFFFu) : ~u);
}

__device__ __forceinline__ void async_load16(void* lds, const void* g) {
    __builtin_amdgcn_global_load_lds(
        (__attribute__((address_space(1))) void*)g,
        (__attribute__((address_space(3))) void*)lds,
        16, 0, 0);
}

// ---------------------------------------------------------------------------
// fp32 -> bf16 elementwise (for colbert_w)
// ---------------------------------------------------------------------------
__global__ void conv_only(const float* __restrict__ src, unsigned short* __restrict__ dst, int n4)
{
    int i = blockIdx.x * blockDim.x + threadIdx.x;
    if (i < n4) {
        float4 x = ((const float4*)src)[i];
        ushort4 o;
        o.x = f2bf(x.x); o.y = f2bf(x.y); o.z = f2bf(x.z); o.w = f2bf(x.w);
        ((ushort4*)dst)[i] = o;
    }
}

// ---------------------------------------------------------------------------
// per hidden row: fp32 -> bf16 copy + sparse token weight
//   tw[row] = relu(dot(hidden[row], sparse_w) + sparse_b)   (fp32 accuracy)
// one block (256 thr) per row of 1024
// ---------------------------------------------------------------------------
__global__ void conv_tw(const float* __restrict__ src, unsigned short* __restrict__ dst,
                        const float* __restrict__ sw, const float* __restrict__ sb,
                        float* __restrict__ tw)
{
    __shared__ float red[4];
    int row = blockIdx.x;
    int t = threadIdx.x;
    const float4* s4 = (const float4*)(src + (size_t)row * 1024);
    const float4* w4 = (const float4*)sw;
    float4 x = s4[t];
    float4 w = w4[t];
    ushort4 o;
    o.x = f2bf(x.x); o.y = f2bf(x.y); o.z = f2bf(x.z); o.w = f2bf(x.w);
    ((ushort4*)dst)[(size_t)row * 256 + t] = o;
    float acc = x.x * w.x + x.y * w.y + x.z * w.z + x.w * w.w;
    #pragma unroll
    for (int s = 32; s; s >>= 1) acc += __shfl_down(acc, s, 64);
    if ((t & 63) == 0) red[t >> 6] = acc;
    __syncthreads();
    if (t == 0) {
        float v = red[0] + red[1] + red[2] + red[3] + sb[0];
        tw[row] = fmaxf(v, 0.0f);
    }
}

// ---------------------------------------------------------------------------
// 128x128x(K) bf16 MFMA GEMM, B^T layout:  C[m,n] = sum_k A[m,k]*B[n,k]
// MODE 0: C_bf16[m,n] = result + bias[n]          (projection)
//         grid: x = row tile, y = col tile  (A-tile sharers land on one XCD)
// MODE 1: fused epilogue: atomicMax of per-(row, p-batch) max, excluding
//         CLS columns (global col % 512 == 0)     (maxsim)
//         grid: x = col tile, y = row tile  (B-tile sharers land on one XCD)
// block = 256 thr (4 waves, 2x2), tile 128x128, BK=32
// LDS layout per 16-row block (1 KB): [k-chunk 0..3][row 0..15] x 16B —
// ds_read_b128 fragment reads are bank-conflict-free (8-lane phase = 32 banks)
// ---------------------------------------------------------------------------
template<int MODE>
__global__ __launch_bounds__(256, 2)
void gemm_bt(const unsigned short* __restrict__ A,
             const unsigned short* __restrict__ B,
             const float* __restrict__ bias,
             unsigned short* __restrict__ C,
             unsigned* __restrict__ Mbuf,
             int M, int N, int K)
{
    __shared__ unsigned short smA[128 * 32];
    __shared__ unsigned short smB[128 * 32];
    const int tid  = threadIdx.x;
    const int lane = tid & 63;
    const int w    = tid >> 6;
    const int wm   = w >> 1, wn = w & 1;
    const int quad = lane >> 4, m16 = lane & 15;
    const int rowTile = (MODE == 0) ? blockIdx.x : blockIdx.y;
    const int colTile = (MODE == 0) ? blockIdx.y : blockIdx.x;
    const int rowBase = rowTile * 128;
    const int colBase = colTile * 128;

    // staging lane decomposition: sr = row within 16-row block, sc = k-chunk.
    // LDS dest is implicitly base + lane*16 -> [sc][sr] transposed layout.
    const int sr = lane & 15, sc = lane >> 4;
    const unsigned short* aG0 = A + (long long)(rowBase + w * 16 + sr) * K + sc * 8;
    const unsigned short* aG1 = aG0 + 64LL * K;
    const unsigned short* bG0 = B + (long long)(colBase + w * 16 + sr) * K + sc * 8;
    const unsigned short* bG1 = bG0 + 64LL * K;
    unsigned short* lA0 = smA + w * 512;
    unsigned short* lA1 = smA + (w + 4) * 512;
    unsigned short* lB0 = smB + w * 512;
    unsigned short* lB1 = smB + (w + 4) * 512;

    floatx4 acc[4][4] = {};

    for (int k0 = 0; k0 < K; k0 += 32) {
        async_load16(lA0, aG0 + k0);
        async_load16(lA1, aG1 + k0);
        async_load16(lB0, bG0 + k0);
        async_load16(lB1, bG1 + k0);
        __syncthreads();
        bf16x8 af[4], bfr[4];
        #pragma unroll
        for (int f = 0; f < 4; ++f) {
            af[f]  = *(const bf16x8*)(smA + (wm * 4 + f) * 512 + quad * 128 + m16 * 8);
            bfr[f] = *(const bf16x8*)(smB + (wn * 4 + f) * 512 + quad * 128 + m16 * 8);
        }
        #pragma unroll
        for (int i = 0; i < 4; ++i)
            #pragma unroll
            for (int j = 0; j < 4; ++j)
                acc[i][j] = __builtin_amdgcn_mfma_f32_16x16x32_bf16(af[i], bfr[j], acc[i][j], 0, 0, 0);
        __syncthreads();
    }

    if (MODE == 0) {
        float bcol[4];
        #pragma unroll
        for (int j = 0; j < 4; ++j) bcol[j] = bias[colBase + wn * 64 + j * 16 + m16];
        #pragma unroll
        for (int i = 0; i < 4; ++i) {
            int row0 = rowBase + wm * 64 + i * 16 + quad * 4;
            #pragma unroll
            for (int r = 0; r < 4; ++r) {
                #pragma unroll
                for (int j = 0; j < 4; ++j) {
                    int col = colBase + wn * 64 + j * 16 + m16;
                    C[(long long)(row0 + r) * N + col] = f2bf(acc[i][j][r] + bcol[j]);
                }
            }
        }
    } else {
        const int pb = colBase >> 9;  // 512 p-tokens per passage
        #pragma unroll
        for (int i = 0; i < 4; ++i) {
            #pragma unroll
            for (int r = 0; r < 4; ++r) {
                float mx = -3.0e38f;
                #pragma unroll
                for (int j = 0; j < 4; ++j) {
                    int colg = colBase + wn * 64 + j * 16 + m16;
                    float v = acc[i][j][r];
                    if ((colg & 511) == 0) v = -3.0e38f;  // exclude CLS column
                    mx = fmaxf(mx, v);
                }
                // max across the 16 lanes of the m16 dimension
                #pragma unroll
                for (int s = 1; s < 16; s <<= 1) mx = fmaxf(mx, __shfl_xor(mx, s, 64));
                if (m16 == 0) {
                    int row = rowBase + wm * 64 + i * 16 + quad * 4 + r;
                    atomicMax(&Mbuf[row * 64 + pb], encf(mx));
                }
            }
        }
    }
}

// ---------------------------------------------------------------------------
// in-place row L2-normalize of bf16 rows (with mask): v = v*m / max(||v*m||,1e-12)
// ---------------------------------------------------------------------------
__global__ void normalize_rows_k(unsigned short* __restrict__ V, const float* __restrict__ mask)
{
    __shared__ float red[4];
    __shared__ float sscale;
    int row = blockIdx.x;
    int t = threadIdx.x;
    float m = mask[row];
    ushort4* v4 = (ushort4*)(V + (size_t)row * 1024);
    ushort4 x = v4[t];
    float f0 = bf2f(x.x) * m, f1 = bf2f(x.y) * m, f2 = bf2f(x.z) * m, f3 = bf2f(x.w) * m;
    float s = f0 * f0 + f1 * f1 + f2 * f2 + f3 * f3;
    #pragma unroll
    for (int sh = 32; sh; sh >>= 1) s += __shfl_down(s, sh, 64);
    if ((t & 63) == 0) red[t >> 6] = s;
    __syncthreads();
    if (t == 0) {
        float n = sqrtf(red[0] + red[1] + red[2] + red[3]);
        sscale = 1.0f / fmaxf(n, 1e-12f);
    }
    __syncthreads();
    float sc = sscale;
    x.x = f2bf(f0 * sc); x.y = f2bf(f1 * sc); x.z = f2bf(f2 * sc); x.w = f2bf(f3 * sc);
    v4[t] = x;
}

// ---------------------------------------------------------------------------
// colbert final reduce: out = sum_{i=1..127} dec(M[i,pb]) / masksum / TEMP
// one wave per (qb,pb) pair
// ---------------------------------------------------------------------------
__global__ void colbert_reduce_k(const unsigned* __restrict__ Mbuf,
                                 const float* __restrict__ q_mask,
                                 float* __restrict__ out)
{
    int pair = blockIdx.x * 4 + (threadIdx.x >> 6);
    int lane = threadIdx.x & 63;
    int qb = pair >> 6, pb = pair & 63;
    float s = 0.0f, msum = 0.0f;
    for (int i = 1 + lane; i < 128; i += 64) {
        s += decf(Mbuf[(qb * 128 + i) * 64 + pb]);
        msum += q_mask[qb * 128 + i];
    }
    #pragma unroll
    for (int sh = 32; sh; sh >>= 1) {
        s += __shfl_down(s, sh, 64);
        msum += __shfl_down(msum, sh, 64);
    }
    if (lane == 0) out[1024 + qb * 64 + pb] = s / msum / TEMP;
}

// ---------------------------------------------------------------------------
// dense: cosine of CLS tokens, fp32 exact. one block per (qb,pb)
// ---------------------------------------------------------------------------
__global__ void dense_scores_k(const float* __restrict__ qh, const float* __restrict__ ph,
                               float* __restrict__ out)
{
    __shared__ float red[12];
    int qb = blockIdx.x >> 6, pb = blockIdx.x & 63;
    int t = threadIdx.x;
    const float4* q4 = (const float4*)(qh + (size_t)qb * 128 * 1024);
    const float4* p4 = (const float4*)(ph + (size_t)pb * 512 * 1024);
    float4 a = q4[t], b = p4[t];
    float dot = a.x * b.x + a.y * b.y + a.z * b.z + a.w * b.w;
    float nq  = a.x * a.x + a.y * a.y + a.z * a.z + a.w * a.w;
    float np  = b.x * b.x + b.y * b.y + b.z * b.z + b.w * b.w;
    #pragma unroll
    for (int sh = 32; sh; sh >>= 1) {
        dot += __shfl_down(dot, sh, 64);
        nq  += __shfl_down(nq, sh, 64);
        np  += __shfl_down(np, sh, 64);
    }
    if ((t & 63) == 0) { int w = t >> 6; red[w] = dot; red[4 + w] = nq; red[8 + w] = np; }
    __syncthreads();
    if (t == 0) {
        dot = red[0] + red[1] + red[2] + red[3];
        nq  = red[4] + red[5] + red[6] + red[7];
        np  = red[8] + red[9] + red[10] + red[11];
        out[qb * 64 + pb] = dot / (fmaxf(sqrtf(nq), 1e-12f) * fmaxf(sqrtf(np), 1e-12f)) / TEMP;
    }
}

// ---------------------------------------------------------------------------
// sparse canonicalization: eff[row,l] = tw if token l is the (unique) argmax
// for its id within the row (ties -> lowest index) and id not in {0,1,2,3}
// throughput version: no break, no divergent loads -> compiler unrolls and
// pipelines the LDS reads (same-address across the wave = broadcast, free).
// grid = (rows, L/256); one token per thread.
// ---------------------------------------------------------------------------
template<int L>
__global__ void sparse_canon_k(const int* __restrict__ ids, const float* __restrict__ tw,
                               float* __restrict__ eff)
{
    __shared__ int   sid[L];
    __shared__ float stw[L];
    int row = blockIdx.x;
    int t = threadIdx.x;
    for (int l = t; l < L; l += 256) { sid[l] = ids[row * L + l]; stw[l] = tw[row * L + l]; }
    __syncthreads();
    int l = blockIdx.y * 256 + t;
    if (l < L) {
        int id = sid[l];
        float wv = stw[l];
        bool kill = (id < 4);  // UNUSED ids {0,1,2,3} -> zero
        #pragma unroll 8
        for (int m = 0; m < L; ++m) {
            int idm = sid[m];
            float wm = stw[m];
            bool beats = (idm == id) & (m != l) & ((wm > wv) | ((wm == wv) & (m < l)));
            kill = kill | beats;
        }
        eff[row * L + l] = kill ? 0.0f : wv;
    }
}

// ---------------------------------------------------------------------------
// sparse scores: sum over matching ids of q_eff * p_eff, one block per pair
// ---------------------------------------------------------------------------
__global__ void sparse_scores_k(const int* __restrict__ q_ids, const float* __restrict__ q_eff,
                                const int* __restrict__ p_ids, const float* __restrict__ p_eff,
                                float* __restrict__ out)
{
    __shared__ int   qid[128];
    __shared__ float qef[128];
    __shared__ int   pid[512];
    __shared__ float pef[512];
    __shared__ float red[4];
    int qb = blockIdx.x >> 6, pb = blockIdx.x & 63;
    int t = threadIdx.x;
    if (t < 128) { qid[t] = q_ids[qb * 128 + t]; qef[t] = q_eff[qb * 128 + t]; }
    for (int m = t; m < 512; m += 256) { pid[m] = p_ids[pb * 512 + m]; pef[m] = p_eff[pb * 512 + m]; }
    __syncthreads();
    float s = 0.0f;
    for (int idx = t; idx < 128 * 512; idx += 256) {
        int l = idx >> 9, m = idx & 511;
        if (qid[l] == pid[m]) s += qef[l] * pef[m];
    }
    #pragma unroll
    for (int sh = 32; sh; sh >>= 1) s += __shfl_down(s, sh, 64);
    if ((t & 63) == 0) red[t >> 6] = s;
    __syncthreads();
    if (t == 0) out[512 + qb * 64 + pb] = (red[0] + red[1] + red[2] + red[3]) / TEMP;
}

// ---------------------------------------------------------------------------
extern "C" void kernel_launch(void* const* d_in, const int* in_sizes, int n_in,
                              void* d_out, int out_size, void* d_ws, size_t ws_size,
                              hipStream_t stream)
{
    const float* q_hidden = (const float*)d_in[0];   // [8,128,1024]
    const float* p_hidden = (const float*)d_in[1];   // [64,512,1024]
    const float* q_mask   = (const float*)d_in[2];   // [8,128]
    const float* p_mask   = (const float*)d_in[3];   // [64,512]
    const int*   q_ids    = (const int*)d_in[4];     // [8,128]
    const int*   p_ids    = (const int*)d_in[5];     // [64,512]
    const float* colbert_w = (const float*)d_in[6];  // [1024,1024]
    const float* colbert_b = (const float*)d_in[7];  // [1024]
    const float* sparse_w  = (const float*)d_in[8];  // [1024]
    const float* sparse_b  = (const float*)d_in[9];  // [1]
    float* out = (float*)d_out;                      // [3*512]

    // workspace carve-up (~141 MB)
    char* ws = (char*)d_ws;
    size_t off = 0;
    auto carve = [&](size_t bytes) { char* p = ws + off; off += (bytes + 255) & ~(size_t)255; return p; };
    unsigned short* Wb   = (unsigned short*)carve((size_t)1024 * 1024 * 2);
    unsigned short* qhb  = (unsigned short*)carve((size_t)1024 * 1024 * 2);
    unsigned short* phb  = (unsigned short*)carve((size_t)32768 * 1024 * 2);
    unsigned short* qv   = (unsigned short*)carve((size_t)1024 * 1024 * 2);
    unsigned short* pv   = (unsigned short*)carve((size_t)32768 * 1024 * 2);
    float*    tw_q  = (float*)carve(1024 * 4);
    float*    tw_p  = (float*)carve(32768 * 4);
    float*    eff_q = (float*)carve(1024 * 4);
    float*    eff_p = (float*)carve(32768 * 4);
    unsigned* Mbuf  = (unsigned*)carve((size_t)1024 * 64 * 4);

    hipMemsetAsync(Mbuf, 0, (size_t)1024 * 64 * 4, stream);

    // bf16 conversions + sparse token weights
    conv_only<<<1024, 256, 0, stream>>>(colbert_w, Wb, 262144);
    conv_tw<<<1024, 256, 0, stream>>>(q_hidden, qhb, sparse_w, sparse_b, tw_q);
    conv_tw<<<32768, 256, 0, stream>>>(p_hidden, phb, sparse_w, sparse_b, tw_p);

    // colbert projection GEMMs: V = X @ W^T + b   (bf16 out)
    // MODE 0 grid: x = row tile, y = col tile (A-tile sharers -> same XCD)
    gemm_bt<0><<<dim3(8, 8), 256, 0, stream>>>(qhb, Wb, colbert_b, qv, nullptr, 1024, 1024, 1024);
    gemm_bt<0><<<dim3(256, 8), 256, 0, stream>>>(phb, Wb, colbert_b, pv, nullptr, 32768, 1024, 1024);

    // mask + L2 normalize rows in place
    normalize_rows_k<<<1024, 256, 0, stream>>>(qv, q_mask);
    normalize_rows_k<<<32768, 256, 0, stream>>>(pv, p_mask);

    // maxsim GEMM with fused max epilogue (x = col tile, y = row tile)
    gemm_bt<1><<<dim3(256, 8), 256, 0, stream>>>(qv, pv, nullptr, nullptr, Mbuf, 1024, 32768, 1024);
    colbert_reduce_k<<<128, 256, 0, stream>>>(Mbuf, q_mask, out);

    // dense
    dense_scores_k<<<512, 256, 0, stream>>>(q_hidden, p_hidden, out);

    // sparse
    sparse_canon_k<128><<<dim3(8, 1), 256, 0, stream>>>(q_ids, tw_q, eff_q);
    sparse_canon_k<512><<<dim3(64, 2), 256, 0, stream>>>(p_ids, tw_p, eff_p);
    sparse_scores_k<<<512, 256, 0, stream>>>(q_ids, eff_q, p_ids, eff_p, out);
}

// Round 4
// 498.074 us; speedup vs baseline: 1.2149x; 1.2149x over previous
//
#include <hip/hip_runtime.h>
#include <hip/hip_bf16.h>

// ---------------------------------------------------------------------------
// BGE-M3 style scoring: dense (CLS cosine), sparse (scatter-max vocab dot),
// colbert (maxsim).  Shapes: q_hidden [8,128,1024], p_hidden [64,512,1024].
// Out = concat(dense[8,64], sparse[8,64], colbert[8,64]) fp32.
// ---------------------------------------------------------------------------

typedef __bf16 bf16x8 __attribute__((ext_vector_type(8)));
typedef float floatx4 __attribute__((ext_vector_type(4)));

#define TEMP 0.02f

__device__ __forceinline__ unsigned short f2bf(float f) {
    unsigned u = __float_as_uint(f);
    unsigned r = (u + 0x7FFFu + ((u >> 16) & 1u)) >> 16;  // RNE
    return (unsigned short)r;
}
__device__ __forceinline__ float bf2f(unsigned short h) {
    return __uint_as_float(((unsigned)h) << 16);
}
// order-preserving float<->uint encode for atomicMax on possibly-negative floats
__device__ __forceinline__ unsigned encf(float f) {
    unsigned u = __float_as_uint(f);
    return (u & 0x80000000u) ? ~u : (u | 0x80000000u);
}
__device__ __forceinline__ float decf(unsigned u) {
    return __uint_as_float((u & 0x80000000u) ? (u & 0x7FFFFFFFu) : ~u);
}

__device__ __forceinline__ void async_load16(void* lds, const void* g) {
    __builtin_amdgcn_global_load_lds(
        (__attribute__((address_space(1))) void*)g,
        (__attribute__((address_space(3))) void*)lds,
        16, 0, 0);
}

// ---------------------------------------------------------------------------
// fp32 -> bf16 elementwise (for colbert_w)
// ---------------------------------------------------------------------------
__global__ void conv_only(const float* __restrict__ src, unsigned short* __restrict__ dst, int n4)
{
    int i = blockIdx.x * blockDim.x + threadIdx.x;
    if (i < n4) {
        float4 x = ((const float4*)src)[i];
        ushort4 o;
        o.x = f2bf(x.x); o.y = f2bf(x.y); o.z = f2bf(x.z); o.w = f2bf(x.w);
        ((ushort4*)dst)[i] = o;
    }
}

// ---------------------------------------------------------------------------
// per hidden row: fp32 -> bf16 copy + sparse token weight
//   tw[row] = relu(dot(hidden[row], sparse_w) + sparse_b)   (fp32 accuracy)
// one block (256 thr) per row of 1024
// ---------------------------------------------------------------------------
__global__ void conv_tw(const float* __restrict__ src, unsigned short* __restrict__ dst,
                        const float* __restrict__ sw, const float* __restrict__ sb,
                        float* __restrict__ tw)
{
    __shared__ float red[4];
    int row = blockIdx.x;
    int t = threadIdx.x;
    const float4* s4 = (const float4*)(src + (size_t)row * 1024);
    const float4* w4 = (const float4*)sw;
    float4 x = s4[t];
    float4 w = w4[t];
    ushort4 o;
    o.x = f2bf(x.x); o.y = f2bf(x.y); o.z = f2bf(x.z); o.w = f2bf(x.w);
    ((ushort4*)dst)[(size_t)row * 256 + t] = o;
    float acc = x.x * w.x + x.y * w.y + x.z * w.z + x.w * w.w;
    #pragma unroll
    for (int s = 32; s; s >>= 1) acc += __shfl_down(acc, s, 64);
    if ((t & 63) == 0) red[t >> 6] = acc;
    __syncthreads();
    if (t == 0) {
        float v = red[0] + red[1] + red[2] + red[3] + sb[0];
        tw[row] = fmaxf(v, 0.0f);
    }
}

// ---------------------------------------------------------------------------
// 128x128x(K) bf16 MFMA GEMM, B^T layout:  C[m,n] = sum_k A[m,k]*B[n,k]
// MODE 0: C_bf16[m,n] = result + bias[n]          (projection)
//         grid: x = row tile, y = col tile  (A-tile sharers land on one XCD)
// MODE 1: fused epilogue: atomicMax of per-(row, p-batch) max, excluding
//         CLS columns (global col % 512 == 0)     (maxsim)
//         grid: x = col tile, y = row tile  (B-tile sharers land on one XCD)
// block = 256 thr (4 waves, 2x2), tile 128x128, BK=32
//
// Staging XOR swizzle: lane l loads row r=l>>2, k-chunk c=(l&3)^((r>>1)&3).
//  - global: each lane quad covers one contiguous 64B segment (coalesced,
//    same as the identity mapping; only within-segment order permuted)
//  - LDS (dest forced to lane*16): fragment (m16, quad) sits at 16B-unit
//    u = 4*m16 + (quad^((m16>>1)&3)); u mod 8 distinct within every 8-lane
//    b128 phase -> bank-conflict-free fragment reads.
// ---------------------------------------------------------------------------
template<int MODE>
__global__ __launch_bounds__(256, 2)
void gemm_bt(const unsigned short* __restrict__ A,
             const unsigned short* __restrict__ B,
             const float* __restrict__ bias,
             unsigned short* __restrict__ C,
             unsigned* __restrict__ Mbuf,
             int M, int N, int K)
{
    __shared__ unsigned short smA[128 * 32];
    __shared__ unsigned short smB[128 * 32];
    const int tid  = threadIdx.x;
    const int lane = tid & 63;
    const int w    = tid >> 6;
    const int wm   = w >> 1, wn = w & 1;
    const int quad = lane >> 4, m16 = lane & 15;
    const int rowTile = (MODE == 0) ? blockIdx.x : blockIdx.y;
    const int colTile = (MODE == 0) ? blockIdx.y : blockIdx.x;
    const int rowBase = rowTile * 128;
    const int colBase = colTile * 128;

    // staging lane decomposition (XOR swizzle)
    const int sr = lane >> 2;
    const int scg = (lane & 3) ^ ((lane >> 3) & 3);
    const unsigned short* aG0 = A + (long long)(rowBase + w * 16 + sr) * K + scg * 8;
    const unsigned short* aG1 = aG0 + 64LL * K;
    const unsigned short* bG0 = B + (long long)(colBase + w * 16 + sr) * K + scg * 8;
    const unsigned short* bG1 = bG0 + 64LL * K;
    unsigned short* lA0 = smA + w * 512;
    unsigned short* lA1 = smA + (w + 4) * 512;
    unsigned short* lB0 = smB + w * 512;
    unsigned short* lB1 = smB + (w + 4) * 512;

    // fragment read offset within a 16-row 1KB LDS block (shorts)
    const int fragOff = (m16 * 4 + (quad ^ ((m16 >> 1) & 3))) * 8;

    floatx4 acc[4][4] = {};

    for (int k0 = 0; k0 < K; k0 += 32) {
        async_load16(lA0, aG0 + k0);
        async_load16(lA1, aG1 + k0);
        async_load16(lB0, bG0 + k0);
        async_load16(lB1, bG1 + k0);
        __syncthreads();
        bf16x8 af[4], bfr[4];
        #pragma unroll
        for (int f = 0; f < 4; ++f) {
            af[f]  = *(const bf16x8*)(smA + (wm * 4 + f) * 512 + fragOff);
            bfr[f] = *(const bf16x8*)(smB + (wn * 4 + f) * 512 + fragOff);
        }
        #pragma unroll
        for (int i = 0; i < 4; ++i)
            #pragma unroll
            for (int j = 0; j < 4; ++j)
                acc[i][j] = __builtin_amdgcn_mfma_f32_16x16x32_bf16(af[i], bfr[j], acc[i][j], 0, 0, 0);
        __syncthreads();
    }

    if (MODE == 0) {
        float bcol[4];
        #pragma unroll
        for (int j = 0; j < 4; ++j) bcol[j] = bias[colBase + wn * 64 + j * 16 + m16];
        #pragma unroll
        for (int i = 0; i < 4; ++i) {
            int row0 = rowBase + wm * 64 + i * 16 + quad * 4;
            #pragma unroll
            for (int r = 0; r < 4; ++r) {
                #pragma unroll
                for (int j = 0; j < 4; ++j) {
                    int col = colBase + wn * 64 + j * 16 + m16;
                    C[(long long)(row0 + r) * N + col] = f2bf(acc[i][j][r] + bcol[j]);
                }
            }
        }
    } else {
        const int pb = colBase >> 9;  // 512 p-tokens per passage
        #pragma unroll
        for (int i = 0; i < 4; ++i) {
            #pragma unroll
            for (int r = 0; r < 4; ++r) {
                float mx = -3.0e38f;
                #pragma unroll
                for (int j = 0; j < 4; ++j) {
                    int colg = colBase + wn * 64 + j * 16 + m16;
                    float v = acc[i][j][r];
                    if ((colg & 511) == 0) v = -3.0e38f;  // exclude CLS column
                    mx = fmaxf(mx, v);
                }
                // max across the 16 lanes of the m16 dimension
                #pragma unroll
                for (int s = 1; s < 16; s <<= 1) mx = fmaxf(mx, __shfl_xor(mx, s, 64));
                if (m16 == 0) {
                    int row = rowBase + wm * 64 + i * 16 + quad * 4 + r;
                    atomicMax(&Mbuf[row * 64 + pb], encf(mx));
                }
            }
        }
    }
}

// ---------------------------------------------------------------------------
// in-place row L2-normalize of bf16 rows (with mask): v = v*m / max(||v*m||,1e-12)
// ---------------------------------------------------------------------------
__global__ void normalize_rows_k(unsigned short* __restrict__ V, const float* __restrict__ mask)
{
    __shared__ float red[4];
    __shared__ float sscale;
    int row = blockIdx.x;
    int t = threadIdx.x;
    float m = mask[row];
    ushort4* v4 = (ushort4*)(V + (size_t)row * 1024);
    ushort4 x = v4[t];
    float f0 = bf2f(x.x) * m, f1 = bf2f(x.y) * m, f2 = bf2f(x.z) * m, f3 = bf2f(x.w) * m;
    float s = f0 * f0 + f1 * f1 + f2 * f2 + f3 * f3;
    #pragma unroll
    for (int sh = 32; sh; sh >>= 1) s += __shfl_down(s, sh, 64);
    if ((t & 63) == 0) red[t >> 6] = s;
    __syncthreads();
    if (t == 0) {
        float n = sqrtf(red[0] + red[1] + red[2] + red[3]);
        sscale = 1.0f / fmaxf(n, 1e-12f);
    }
    __syncthreads();
    float sc = sscale;
    x.x = f2bf(f0 * sc); x.y = f2bf(f1 * sc); x.z = f2bf(f2 * sc); x.w = f2bf(f3 * sc);
    v4[t] = x;
}

// ---------------------------------------------------------------------------
// colbert final reduce: out = sum_{i=1..127} dec(M[i,pb]) / masksum / TEMP
// one wave per (qb,pb) pair
// ---------------------------------------------------------------------------
__global__ void colbert_reduce_k(const unsigned* __restrict__ Mbuf,
                                 const float* __restrict__ q_mask,
                                 float* __restrict__ out)
{
    int pair = blockIdx.x * 4 + (threadIdx.x >> 6);
    int lane = threadIdx.x & 63;
    int qb = pair >> 6, pb = pair & 63;
    float s = 0.0f, msum = 0.0f;
    for (int i = 1 + lane; i < 128; i += 64) {
        s += decf(Mbuf[(qb * 128 + i) * 64 + pb]);
        msum += q_mask[qb * 128 + i];
    }
    #pragma unroll
    for (int sh = 32; sh; sh >>= 1) {
        s += __shfl_down(s, sh, 64);
        msum += __shfl_down(msum, sh, 64);
    }
    if (lane == 0) out[1024 + qb * 64 + pb] = s / msum / TEMP;
}

// ---------------------------------------------------------------------------
// dense: cosine of CLS tokens, fp32 exact. one block per (qb,pb)
// ---------------------------------------------------------------------------
__global__ void dense_scores_k(const float* __restrict__ qh, const float* __restrict__ ph,
                               float* __restrict__ out)
{
    __shared__ float red[12];
    int qb = blockIdx.x >> 6, pb = blockIdx.x & 63;
    int t = threadIdx.x;
    const float4* q4 = (const float4*)(qh + (size_t)qb * 128 * 1024);
    const float4* p4 = (const float4*)(ph + (size_t)pb * 512 * 1024);
    float4 a = q4[t], b = p4[t];
    float dot = a.x * b.x + a.y * b.y + a.z * b.z + a.w * b.w;
    float nq  = a.x * a.x + a.y * a.y + a.z * a.z + a.w * a.w;
    float np  = b.x * b.x + b.y * b.y + b.z * b.z + b.w * b.w;
    #pragma unroll
    for (int sh = 32; sh; sh >>= 1) {
        dot += __shfl_down(dot, sh, 64);
        nq  += __shfl_down(nq, sh, 64);
        np  += __shfl_down(np, sh, 64);
    }
    if ((t & 63) == 0) { int w = t >> 6; red[w] = dot; red[4 + w] = nq; red[8 + w] = np; }
    __syncthreads();
    if (t == 0) {
        dot = red[0] + red[1] + red[2] + red[3];
        nq  = red[4] + red[5] + red[6] + red[7];
        np  = red[8] + red[9] + red[10] + red[11];
        out[qb * 64 + pb] = dot / (fmaxf(sqrtf(nq), 1e-12f) * fmaxf(sqrtf(np), 1e-12f)) / TEMP;
    }
}

// ---------------------------------------------------------------------------
// sparse canonicalization: eff[row,l] = tw if token l is the (unique) argmax
// for its id within the row (ties -> lowest index) and id not in {0,1,2,3}
// grid = (rows, L/256); one token per thread.
// ---------------------------------------------------------------------------
template<int L>
__global__ void sparse_canon_k(const int* __restrict__ ids, const float* __restrict__ tw,
                               float* __restrict__ eff)
{
    __shared__ int   sid[L];
    __shared__ float stw[L];
    int row = blockIdx.x;
    int t = threadIdx.x;
    for (int l = t; l < L; l += 256) { sid[l] = ids[row * L + l]; stw[l] = tw[row * L + l]; }
    __syncthreads();
    int l = blockIdx.y * 256 + t;
    if (l < L) {
        int id = sid[l];
        float wv = stw[l];
        bool kill = (id < 4);  // UNUSED ids {0,1,2,3} -> zero
        #pragma unroll 8
        for (int m = 0; m < L; ++m) {
            int idm = sid[m];
            float wm = stw[m];
            bool beats = (idm == id) & (m != l) & ((wm > wv) | ((wm == wv) & (m < l)));
            kill = kill | beats;
        }
        eff[row * L + l] = kill ? 0.0f : wv;
    }
}

// ---------------------------------------------------------------------------
// sparse scores: sum over matching ids of q_eff * p_eff, one block per pair
// ---------------------------------------------------------------------------
__global__ void sparse_scores_k(const int* __restrict__ q_ids, const float* __restrict__ q_eff,
                                const int* __restrict__ p_ids, const float* __restrict__ p_eff,
                                float* __restrict__ out)
{
    __shared__ int   qid[128];
    __shared__ float qef[128];
    __shared__ int   pid[512];
    __shared__ float pef[512];
    __shared__ float red[4];
    int qb = blockIdx.x >> 6, pb = blockIdx.x & 63;
    int t = threadIdx.x;
    if (t < 128) { qid[t] = q_ids[qb * 128 + t]; qef[t] = q_eff[qb * 128 + t]; }
    for (int m = t; m < 512; m += 256) { pid[m] = p_ids[pb * 512 + m]; pef[m] = p_eff[pb * 512 + m]; }
    __syncthreads();
    float s = 0.0f;
    for (int idx = t; idx < 128 * 512; idx += 256) {
        int l = idx >> 9, m = idx & 511;
        if (qid[l] == pid[m]) s += qef[l] * pef[m];
    }
    #pragma unroll
    for (int sh = 32; sh; sh >>= 1) s += __shfl_down(s, sh, 64);
    if ((t & 63) == 0) red[t >> 6] = s;
    __syncthreads();
    if (t == 0) out[512 + qb * 64 + pb] = (red[0] + red[1] + red[2] + red[3]) / TEMP;
}

// ---------------------------------------------------------------------------
extern "C" void kernel_launch(void* const* d_in, const int* in_sizes, int n_in,
                              void* d_out, int out_size, void* d_ws, size_t ws_size,
                              hipStream_t stream)
{
    const float* q_hidden = (const float*)d_in[0];   // [8,128,1024]
    const float* p_hidden = (const float*)d_in[1];   // [64,512,1024]
    const float* q_mask   = (const float*)d_in[2];   // [8,128]
    const float* p_mask   = (const float*)d_in[3];   // [64,512]
    const int*   q_ids    = (const int*)d_in[4];     // [8,128]
    const int*   p_ids    = (const int*)d_in[5];     // [64,512]
    const float* colbert_w = (const float*)d_in[6];  // [1024,1024]
    const float* colbert_b = (const float*)d_in[7];  // [1024]
    const float* sparse_w  = (const float*)d_in[8];  // [1024]
    const float* sparse_b  = (const float*)d_in[9];  // [1]
    float* out = (float*)d_out;                      // [3*512]

    // workspace carve-up (~141 MB)
    char* ws = (char*)d_ws;
    size_t off = 0;
    auto carve = [&](size_t bytes) { char* p = ws + off; off += (bytes + 255) & ~(size_t)255; return p; };
    unsigned short* Wb   = (unsigned short*)carve((size_t)1024 * 1024 * 2);
    unsigned short* qhb  = (unsigned short*)carve((size_t)1024 * 1024 * 2);
    unsigned short* phb  = (unsigned short*)carve((size_t)32768 * 1024 * 2);
    unsigned short* qv   = (unsigned short*)carve((size_t)1024 * 1024 * 2);
    unsigned short* pv   = (unsigned short*)carve((size_t)32768 * 1024 * 2);
    float*    tw_q  = (float*)carve(1024 * 4);
    float*    tw_p  = (float*)carve(32768 * 4);
    float*    eff_q = (float*)carve(1024 * 4);
    float*    eff_p = (float*)carve(32768 * 4);
    unsigned* Mbuf  = (unsigned*)carve((size_t)1024 * 64 * 4);

    hipMemsetAsync(Mbuf, 0, (size_t)1024 * 64 * 4, stream);

    // bf16 conversions + sparse token weights
    conv_only<<<1024, 256, 0, stream>>>(colbert_w, Wb, 262144);
    conv_tw<<<1024, 256, 0, stream>>>(q_hidden, qhb, sparse_w, sparse_b, tw_q);
    conv_tw<<<32768, 256, 0, stream>>>(p_hidden, phb, sparse_w, sparse_b, tw_p);

    // colbert projection GEMMs: V = X @ W^T + b   (bf16 out)
    // MODE 0 grid: x = row tile, y = col tile (A-tile sharers -> same XCD)
    gemm_bt<0><<<dim3(8, 8), 256, 0, stream>>>(qhb, Wb, colbert_b, qv, nullptr, 1024, 1024, 1024);
    gemm_bt<0><<<dim3(256, 8), 256, 0, stream>>>(phb, Wb, colbert_b, pv, nullptr, 32768, 1024, 1024);

    // mask + L2 normalize rows in place
    normalize_rows_k<<<1024, 256, 0, stream>>>(qv, q_mask);
    normalize_rows_k<<<32768, 256, 0, stream>>>(pv, p_mask);

    // maxsim GEMM with fused max epilogue (x = col tile, y = row tile)
    gemm_bt<1><<<dim3(256, 8), 256, 0, stream>>>(qv, pv, nullptr, nullptr, Mbuf, 1024, 32768, 1024);
    colbert_reduce_k<<<128, 256, 0, stream>>>(Mbuf, q_mask, out);

    // dense
    dense_scores_k<<<512, 256, 0, stream>>>(q_hidden, p_hidden, out);

    // sparse
    sparse_canon_k<128><<<dim3(8, 1), 256, 0, stream>>>(q_ids, tw_q, eff_q);
    sparse_canon_k<512><<<dim3(64, 2), 256, 0, stream>>>(p_ids, tw_p, eff_p);
    sparse_scores_k<<<512, 256, 0, stream>>>(q_ids, eff_q, p_ids, eff_p, out);
}

// Round 5
// 438.735 us; speedup vs baseline: 1.3792x; 1.1353x over previous
//
#include <hip/hip_runtime.h>
#include <hip/hip_bf16.h>

// ---------------------------------------------------------------------------
// BGE-M3 style scoring: dense (CLS cosine), sparse (scatter-max vocab dot),
// colbert (maxsim).  Shapes: q_hidden [8,128,1024], p_hidden [64,512,1024].
// Out = concat(dense[8,64], sparse[8,64], colbert[8,64]) fp32.
//
// Deferred-normalization colbert: projection GEMM stores RAW projected rows
// (bf16) + accumulates normsq[row]; maxsim epilogue applies per-column factor
// pfac_j = m_j / max(||v_j||*m_j, eps) before the max (max commutes with the
// per-row factor, applied later in colbert_reduce).
// ---------------------------------------------------------------------------

typedef __bf16 bf16x8 __attribute__((ext_vector_type(8)));
typedef float floatx4 __attribute__((ext_vector_type(4)));

#define TEMP 0.02f

__device__ __forceinline__ unsigned short f2bf(float f) {
    unsigned u = __float_as_uint(f);
    unsigned r = (u + 0x7FFFu + ((u >> 16) & 1u)) >> 16;  // RNE
    return (unsigned short)r;
}
__device__ __forceinline__ float bf2f(unsigned short h) {
    return __uint_as_float(((unsigned)h) << 16);
}
// order-preserving float<->uint encode for atomicMax on possibly-negative floats
__device__ __forceinline__ unsigned encf(float f) {
    unsigned u = __float_as_uint(f);
    return (u & 0x80000000u) ? ~u : (u | 0x80000000u);
}
__device__ __forceinline__ float decf(unsigned u) {
    return __uint_as_float((u & 0x80000000u) ? (u & 0x7FFFFFFFu) : ~u);
}

__device__ __forceinline__ void async_load16(void* lds, const void* g) {
    __builtin_amdgcn_global_load_lds(
        (__attribute__((address_space(1))) void*)g,
        (__attribute__((address_space(3))) void*)lds,
        16, 0, 0);
}

// ---------------------------------------------------------------------------
// fused fp32->bf16 conversion for q_hidden / p_hidden / colbert_w into one
// contiguous bf16 buffer, + sparse token weight for hidden rows.
// rows: [0,1024) = q, [1024,33792) = p, [33792,34816) = colbert_w
// ---------------------------------------------------------------------------
__global__ void conv_fused(const float* __restrict__ qh, const float* __restrict__ ph,
                           const float* __restrict__ wsrc, unsigned short* __restrict__ dst,
                           const float* __restrict__ sw, const float* __restrict__ sb,
                           float* __restrict__ tw)
{
    __shared__ float red[4];
    int row = blockIdx.x;
    int t = threadIdx.x;
    const float* src;
    bool do_tw;
    if (row < 1024)       { src = qh   + (size_t)row * 1024;            do_tw = true;  }
    else if (row < 33792) { src = ph   + (size_t)(row - 1024) * 1024;   do_tw = true;  }
    else                  { src = wsrc + (size_t)(row - 33792) * 1024;  do_tw = false; }
    const float4* s4 = (const float4*)src;
    const float4* w4 = (const float4*)sw;
    float4 x = s4[t];
    ushort4 o;
    o.x = f2bf(x.x); o.y = f2bf(x.y); o.z = f2bf(x.z); o.w = f2bf(x.w);
    ((ushort4*)dst)[(size_t)row * 256 + t] = o;
    if (do_tw) {
        float4 w = w4[t];
        float acc = x.x * w.x + x.y * w.y + x.z * w.z + x.w * w.w;
        #pragma unroll
        for (int s = 32; s; s >>= 1) acc += __shfl_down(acc, s, 64);
        if ((t & 63) == 0) red[t >> 6] = acc;
        __syncthreads();
        if (t == 0) {
            float v = red[0] + red[1] + red[2] + red[3] + sb[0];
            tw[row] = fmaxf(v, 0.0f);
        }
    }
}

// ---------------------------------------------------------------------------
// 128x128xK bf16 MFMA GEMM, B^T layout:  C[m,n] = sum_k A[m,k]*B[n,k]
// tile 128x128, BK=64 (2 barriers per 32 MFMA), 256 thr (4 waves, 2x2).
// MODE 0 (projection): C_bf16 = result + bias[n]; atomicAdd normsq[row] of
//         row sum-of-squares.  grid: x = row tile, y = col tile.
// MODE 1 (maxsim): scale col j by pfac_j = pm/max(||v_j||*pm,eps), exclude
//         CLS cols (col%512==0), row-max -> atomicMax Mbuf[row*64 + pbatch].
//         grid: x = col tile, y = row tile.
//
// Staging XOR swizzle (verified R4): lane l loads row r=l>>2, k-chunk
// c=(l&3)^((l>>3)&3); global stays 64B-segment coalesced, LDS fragment
// reads land conflict-free at fragOff = (m16*4 + (quad^((m16>>1)&3)))*8.
// ---------------------------------------------------------------------------
template<int MODE>
__global__ __launch_bounds__(256, 2)
void gemm_bt(const unsigned short* __restrict__ A,
             const unsigned short* __restrict__ B,
             const float* __restrict__ bias,
             unsigned short* __restrict__ C,
             unsigned* __restrict__ Mbuf,
             float* __restrict__ normsq,
             const float* __restrict__ p_mask,
             int M, int N, int K)
{
    __shared__ unsigned short smA[128 * 64];
    __shared__ unsigned short smB[128 * 64];
    const int tid  = threadIdx.x;
    const int lane = tid & 63;
    const int w    = tid >> 6;
    const int wm   = w >> 1, wn = w & 1;
    const int quad = lane >> 4, m16 = lane & 15;
    const int rowTile = (MODE == 0) ? blockIdx.x : blockIdx.y;
    const int colTile = (MODE == 0) ? blockIdx.y : blockIdx.x;
    const int rowBase = rowTile * 128;
    const int colBase = colTile * 128;

    // staging lane decomposition (XOR swizzle)
    const int sr = lane >> 2;
    const int scg = (lane & 3) ^ ((lane >> 3) & 3);
    // chunk c covers rows 16c..16c+15; wave w stages chunks {w, w+4} for both k-halves
    const unsigned short* aG0 = A + (long long)(rowBase + w * 16 + sr) * K + scg * 8;
    const unsigned short* aG1 = aG0 + 64LL * K;
    const unsigned short* bG0 = B + (long long)(colBase + w * 16 + sr) * K + scg * 8;
    const unsigned short* bG1 = bG0 + 64LL * K;
    unsigned short* lA0 = smA + w * 512;          // khalf 0 at +0, khalf 1 at +4096
    unsigned short* lA1 = smA + (w + 4) * 512;
    unsigned short* lB0 = smB + w * 512;
    unsigned short* lB1 = smB + (w + 4) * 512;

    const int fragOff = (m16 * 4 + (quad ^ ((m16 >> 1) & 3))) * 8;

    floatx4 acc[4][4] = {};

    for (int k0 = 0; k0 < K; k0 += 64) {
        async_load16(lA0,        aG0 + k0);
        async_load16(lA0 + 4096, aG0 + k0 + 32);
        async_load16(lA1,        aG1 + k0);
        async_load16(lA1 + 4096, aG1 + k0 + 32);
        async_load16(lB0,        bG0 + k0);
        async_load16(lB0 + 4096, bG0 + k0 + 32);
        async_load16(lB1,        bG1 + k0);
        async_load16(lB1 + 4096, bG1 + k0 + 32);
        __syncthreads();
        #pragma unroll
        for (int h = 0; h < 2; ++h) {
            bf16x8 af[4], bfr[4];
            #pragma unroll
            for (int f = 0; f < 4; ++f) {
                af[f]  = *(const bf16x8*)(smA + h * 4096 + (wm * 4 + f) * 512 + fragOff);
                bfr[f] = *(const bf16x8*)(smB + h * 4096 + (wn * 4 + f) * 512 + fragOff);
            }
            #pragma unroll
            for (int i = 0; i < 4; ++i)
                #pragma unroll
                for (int j = 0; j < 4; ++j)
                    acc[i][j] = __builtin_amdgcn_mfma_f32_16x16x32_bf16(af[i], bfr[j], acc[i][j], 0, 0, 0);
        }
        __syncthreads();
    }

    if (MODE == 0) {
        float bcol[4];
        #pragma unroll
        for (int j = 0; j < 4; ++j) bcol[j] = bias[colBase + wn * 64 + j * 16 + m16];
        #pragma unroll
        for (int i = 0; i < 4; ++i) {
            int row0 = rowBase + wm * 64 + i * 16 + quad * 4;
            #pragma unroll
            for (int r = 0; r < 4; ++r) {
                float sq = 0.0f;
                #pragma unroll
                for (int j = 0; j < 4; ++j) {
                    int col = colBase + wn * 64 + j * 16 + m16;
                    float val = acc[i][j][r] + bcol[j];
                    C[(long long)(row0 + r) * N + col] = f2bf(val);
                    sq += val * val;
                }
                // reduce over the 16 m16 lanes (same quad -> same row)
                #pragma unroll
                for (int s = 1; s < 16; s <<= 1) sq += __shfl_xor(sq, s, 64);
                if (m16 == 0) atomicAdd(&normsq[row0 + r], sq);
            }
        }
    } else {
        const int pb = colBase >> 9;  // 512 p-tokens per passage
        float pfac[4];
        #pragma unroll
        for (int j = 0; j < 4; ++j) {
            int colg = colBase + wn * 64 + j * 16 + m16;
            float pm = p_mask[colg];
            float pn = sqrtf(normsq[1024 + colg]);
            pfac[j] = pm / fmaxf(pn * pm, 1e-12f);
        }
        #pragma unroll
        for (int i = 0; i < 4; ++i) {
            #pragma unroll
            for (int r = 0; r < 4; ++r) {
                float mx = -3.0e38f;
                #pragma unroll
                for (int j = 0; j < 4; ++j) {
                    int colg = colBase + wn * 64 + j * 16 + m16;
                    float v = acc[i][j][r] * pfac[j];
                    if ((colg & 511) == 0) v = -3.0e38f;  // exclude CLS column
                    mx = fmaxf(mx, v);
                }
                #pragma unroll
                for (int s = 1; s < 16; s <<= 1) mx = fmaxf(mx, __shfl_xor(mx, s, 64));
                if (m16 == 0) {
                    int row = rowBase + wm * 64 + i * 16 + quad * 4 + r;
                    atomicMax(&Mbuf[row * 64 + pb], encf(mx));
                }
            }
        }
    }
}

// ---------------------------------------------------------------------------
// colbert final reduce: out = sum_{i>=1} dec(M[i,pb])*qfac_i / msum / TEMP
// qfac_i = qm/max(||v_i||*qm, eps)  (the deferred per-row normalization)
// one wave per (qb,pb) pair
// ---------------------------------------------------------------------------
__global__ void colbert_reduce_k(const unsigned* __restrict__ Mbuf,
                                 const float* __restrict__ q_mask,
                                 const float* __restrict__ normsq,
                                 float* __restrict__ out)
{
    int pair = blockIdx.x * 4 + (threadIdx.x >> 6);
    int lane = threadIdx.x & 63;
    int qb = pair >> 6, pb = pair & 63;
    float s = 0.0f, msum = 0.0f;
    for (int i = 1 + lane; i < 128; i += 64) {
        float qm = q_mask[qb * 128 + i];
        float qn = sqrtf(normsq[qb * 128 + i]);
        float qfac = qm / fmaxf(qn * qm, 1e-12f);
        s += decf(Mbuf[(qb * 128 + i) * 64 + pb]) * qfac;
        msum += qm;
    }
    #pragma unroll
    for (int sh = 32; sh; sh >>= 1) {
        s += __shfl_down(s, sh, 64);
        msum += __shfl_down(msum, sh, 64);
    }
    if (lane == 0) out[1024 + qb * 64 + pb] = s / msum / TEMP;
}

// ---------------------------------------------------------------------------
// dense: cosine of CLS tokens, fp32 exact. one block per (qb,pb)
// ---------------------------------------------------------------------------
__global__ void dense_scores_k(const float* __restrict__ qh, const float* __restrict__ ph,
                               float* __restrict__ out)
{
    __shared__ float red[12];
    int qb = blockIdx.x >> 6, pb = blockIdx.x & 63;
    int t = threadIdx.x;
    const float4* q4 = (const float4*)(qh + (size_t)qb * 128 * 1024);
    const float4* p4 = (const float4*)(ph + (size_t)pb * 512 * 1024);
    float4 a = q4[t], b = p4[t];
    float dot = a.x * b.x + a.y * b.y + a.z * b.z + a.w * b.w;
    float nq  = a.x * a.x + a.y * a.y + a.z * a.z + a.w * a.w;
    float np  = b.x * b.x + b.y * b.y + b.z * b.z + b.w * b.w;
    #pragma unroll
    for (int sh = 32; sh; sh >>= 1) {
        dot += __shfl_down(dot, sh, 64);
        nq  += __shfl_down(nq, sh, 64);
        np  += __shfl_down(np, sh, 64);
    }
    if ((t & 63) == 0) { int w = t >> 6; red[w] = dot; red[4 + w] = nq; red[8 + w] = np; }
    __syncthreads();
    if (t == 0) {
        dot = red[0] + red[1] + red[2] + red[3];
        nq  = red[4] + red[5] + red[6] + red[7];
        np  = red[8] + red[9] + red[10] + red[11];
        out[qb * 64 + pb] = dot / (fmaxf(sqrtf(nq), 1e-12f) * fmaxf(sqrtf(np), 1e-12f)) / TEMP;
    }
}

// ---------------------------------------------------------------------------
// sparse canonicalization: eff[row,l] = tw if token l is the (unique) argmax
// for its id within the row (ties -> lowest index) and id not in {0,1,2,3}
// grid = (rows, L/256); one token per thread.
// ---------------------------------------------------------------------------
template<int L>
__global__ void sparse_canon_k(const int* __restrict__ ids, const float* __restrict__ tw,
                               float* __restrict__ eff)
{
    __shared__ int   sid[L];
    __shared__ float stw[L];
    int row = blockIdx.x;
    int t = threadIdx.x;
    for (int l = t; l < L; l += 256) { sid[l] = ids[row * L + l]; stw[l] = tw[row * L + l]; }
    __syncthreads();
    int l = blockIdx.y * 256 + t;
    if (l < L) {
        int id = sid[l];
        float wv = stw[l];
        bool kill = (id < 4);  // UNUSED ids {0,1,2,3} -> zero
        #pragma unroll 8
        for (int m = 0; m < L; ++m) {
            int idm = sid[m];
            float wm = stw[m];
            bool beats = (idm == id) & (m != l) & ((wm > wv) | ((wm == wv) & (m < l)));
            kill = kill | beats;
        }
        eff[row * L + l] = kill ? 0.0f : wv;
    }
}

// ---------------------------------------------------------------------------
// sparse scores: sum over matching ids of q_eff * p_eff, one block per pair
// ---------------------------------------------------------------------------
__global__ void sparse_scores_k(const int* __restrict__ q_ids, const float* __restrict__ q_eff,
                                const int* __restrict__ p_ids, const float* __restrict__ p_eff,
                                float* __restrict__ out)
{
    __shared__ int   qid[128];
    __shared__ float qef[128];
    __shared__ int   pid[512];
    __shared__ float pef[512];
    __shared__ float red[4];
    int qb = blockIdx.x >> 6, pb = blockIdx.x & 63;
    int t = threadIdx.x;
    if (t < 128) { qid[t] = q_ids[qb * 128 + t]; qef[t] = q_eff[qb * 128 + t]; }
    for (int m = t; m < 512; m += 256) { pid[m] = p_ids[pb * 512 + m]; pef[m] = p_eff[pb * 512 + m]; }
    __syncthreads();
    float s = 0.0f;
    for (int idx = t; idx < 128 * 512; idx += 256) {
        int l = idx >> 9, m = idx & 511;
        if (qid[l] == pid[m]) s += qef[l] * pef[m];
    }
    #pragma unroll
    for (int sh = 32; sh; sh >>= 1) s += __shfl_down(s, sh, 64);
    if ((t & 63) == 0) red[t >> 6] = s;
    __syncthreads();
    if (t == 0) out[512 + qb * 64 + pb] = (red[0] + red[1] + red[2] + red[3]) / TEMP;
}

// ---------------------------------------------------------------------------
extern "C" void kernel_launch(void* const* d_in, const int* in_sizes, int n_in,
                              void* d_out, int out_size, void* d_ws, size_t ws_size,
                              hipStream_t stream)
{
    const float* q_hidden = (const float*)d_in[0];   // [8,128,1024]
    const float* p_hidden = (const float*)d_in[1];   // [64,512,1024]
    const float* q_mask   = (const float*)d_in[2];   // [8,128]
    const float* p_mask   = (const float*)d_in[3];   // [64,512]
    const int*   q_ids    = (const int*)d_in[4];     // [8,128]
    const int*   p_ids    = (const int*)d_in[5];     // [64,512]
    const float* colbert_w = (const float*)d_in[6];  // [1024,1024]
    const float* colbert_b = (const float*)d_in[7];  // [1024]
    const float* sparse_w  = (const float*)d_in[8];  // [1024]
    const float* sparse_b  = (const float*)d_in[9];  // [1]
    float* out = (float*)d_out;                      // [3*512]

    // workspace carve-up (~135 MB). qhb|phb|Wb contiguous; qv|pv contiguous;
    // Mbuf|normsq contiguous (single memset).
    char* ws = (char*)d_ws;
    size_t off = 0;
    auto carve = [&](size_t bytes) { char* p = ws + off; off += (bytes + 255) & ~(size_t)255; return p; };
    unsigned short* qhb  = (unsigned short*)carve((size_t)1024 * 1024 * 2);
    unsigned short* phb  = (unsigned short*)carve((size_t)32768 * 1024 * 2);
    unsigned short* Wb   = (unsigned short*)carve((size_t)1024 * 1024 * 2);
    unsigned short* qv   = (unsigned short*)carve((size_t)1024 * 1024 * 2);
    unsigned short* pv   = (unsigned short*)carve((size_t)32768 * 1024 * 2);
    unsigned* Mbuf  = (unsigned*)carve((size_t)1024 * 64 * 4);
    float*    normsq = (float*)carve((size_t)33792 * 4);
    float*    tw    = (float*)carve((size_t)33792 * 4);
    float*    eff_q = (float*)carve(1024 * 4);
    float*    eff_p = (float*)carve(32768 * 4);
    (void)phb; (void)Wb; (void)pv;

    // zero Mbuf + normsq in one shot (they are adjacent)
    hipMemsetAsync(Mbuf, 0, (size_t)1024 * 64 * 4 + (size_t)33792 * 4, stream);

    // fused bf16 conversion (q, p, W) + sparse token weights
    conv_fused<<<34816, 256, 0, stream>>>(q_hidden, p_hidden, colbert_w, qhb,
                                          sparse_w, sparse_b, tw);

    // single projection GEMM over concat(q,p): V = X @ W^T + b, raw bf16 out,
    // + normsq accumulation.  grid: x = row tile (264), y = col tile (8).
    gemm_bt<0><<<dim3(264, 8), 256, 0, stream>>>(qhb, Wb, colbert_b, qv,
                                                 nullptr, normsq, nullptr,
                                                 33792, 1024, 1024);

    // maxsim GEMM with fused per-col normalization + max epilogue
    gemm_bt<1><<<dim3(256, 8), 256, 0, stream>>>(qv, pv, nullptr, nullptr,
                                                 Mbuf, normsq, p_mask,
                                                 1024, 32768, 1024);
    colbert_reduce_k<<<128, 256, 0, stream>>>(Mbuf, q_mask, normsq, out);

    // dense
    dense_scores_k<<<512, 256, 0, stream>>>(q_hidden, p_hidden, out);

    // sparse (tw layout: rows 0..1023 = q tokens, 1024..33791 = p tokens)
    sparse_canon_k<128><<<dim3(8, 1), 256, 0, stream>>>(q_ids, tw, eff_q);
    sparse_canon_k<512><<<dim3(64, 2), 256, 0, stream>>>(p_ids, tw + 1024, eff_p);
    sparse_scores_k<<<512, 256, 0, stream>>>(q_ids, eff_q, p_ids, eff_p, out);
}

// Round 6
// 410.272 us; speedup vs baseline: 1.4749x; 1.0694x over previous
//
#include <hip/hip_runtime.h>
#include <hip/hip_bf16.h>

// ---------------------------------------------------------------------------
// BGE-M3 style scoring: dense (CLS cosine), sparse (scatter-max vocab dot),
// colbert (maxsim).  Shapes: q_hidden [8,128,1024], p_hidden [64,512,1024].
// Out = concat(dense[8,64], sparse[8,64], colbert[8,64]) fp32.
//
// 5-dispatch pipeline:
//   1. conv_zero_tw : fp32->bf16 cast (q|p|W), token weights, zero Mbuf/normsq
//   2. canon_all    : sparse canonicalization (q + p in one grid)
//   3. gemm_bt<0>   : projection GEMM (+normsq) with dense+sparse tail blocks
//   4. gemm_bt<1>   : maxsim GEMM with fused per-col normalization + max
//   5. colbert_reduce
// ---------------------------------------------------------------------------

typedef __bf16 bf16x8 __attribute__((ext_vector_type(8)));
typedef float floatx4 __attribute__((ext_vector_type(4)));
typedef unsigned short ushort8v __attribute__((ext_vector_type(8)));

#define TEMP 0.02f

__device__ __forceinline__ unsigned short f2bf(float f) {
    unsigned u = __float_as_uint(f);
    unsigned r = (u + 0x7FFFu + ((u >> 16) & 1u)) >> 16;  // RNE
    return (unsigned short)r;
}
// order-preserving float<->uint encode for atomicMax on possibly-negative floats
__device__ __forceinline__ unsigned encf(float f) {
    unsigned u = __float_as_uint(f);
    return (u & 0x80000000u) ? ~u : (u | 0x80000000u);
}
__device__ __forceinline__ float decf(unsigned u) {
    return __uint_as_float((u & 0x80000000u) ? (u & 0x7FFFFFFFu) : ~u);
}

__device__ __forceinline__ void async_load16(void* lds, const void* g) {
    __builtin_amdgcn_global_load_lds(
        (__attribute__((address_space(1))) void*)g,
        (__attribute__((address_space(3))) void*)lds,
        16, 0, 0);
}

// ---------------------------------------------------------------------------
// conv_zero_tw: 2 rows per block (17408 blocks).
//  - fp32 -> bf16 cast of q_hidden / p_hidden / colbert_w into one buffer
//    (rows [0,1024)=q, [1024,33792)=p, [33792,34816)=W), ushort8 16B stores
//  - sparse token weight tw[row] = relu(dot(row, sparse_w) + sb) for hidden rows
//  - blocks [0,388) also zero Mbuf+normsq (388*256 words = 97+33 KB exactly)
// ---------------------------------------------------------------------------
__global__ void conv_zero_tw(const float* __restrict__ qh, const float* __restrict__ ph,
                             const float* __restrict__ wsrc, unsigned short* __restrict__ dst,
                             const float* __restrict__ sw, const float* __restrict__ sb,
                             float* __restrict__ tw, unsigned* __restrict__ zbase)
{
    __shared__ float red[4];
    int b = blockIdx.x, t = threadIdx.x;
    if (b < 388) zbase[b * 256 + t] = 0u;
    int r0 = b * 2;
    const float* src;
    bool do_tw = true;
    if (r0 < 1024)       { src = qh   + (size_t)r0 * 1024; }
    else if (r0 < 33792) { src = ph   + (size_t)(r0 - 1024) * 1024; }
    else                 { src = wsrc + (size_t)(r0 - 33792) * 1024; do_tw = false; }
    const float4* s4 = (const float4*)src;
    float4 a = s4[t * 2], c = s4[t * 2 + 1];   // 8 consecutive floats per thread
    ushort8v o;
    o[0] = f2bf(a.x); o[1] = f2bf(a.y); o[2] = f2bf(a.z); o[3] = f2bf(a.w);
    o[4] = f2bf(c.x); o[5] = f2bf(c.y); o[6] = f2bf(c.z); o[7] = f2bf(c.w);
    ((ushort8v*)dst)[(size_t)b * 256 + t] = o;
    if (do_tw) {
        const float4* w4 = (const float4*)sw;
        int wi = (t & 127) * 2;
        float4 wa = w4[wi], wc = w4[wi + 1];
        float acc = a.x * wa.x + a.y * wa.y + a.z * wa.z + a.w * wa.w
                  + c.x * wc.x + c.y * wc.y + c.z * wc.z + c.w * wc.w;
        #pragma unroll
        for (int s = 32; s; s >>= 1) acc += __shfl_down(acc, s, 64);
        if ((t & 63) == 0) red[t >> 6] = acc;   // waves 0,1 -> row r0; 2,3 -> r0+1
        __syncthreads();
        if (t == 0)   tw[r0]     = fmaxf(red[0] + red[1] + sb[0], 0.0f);
        if (t == 128) tw[r0 + 1] = fmaxf(red[2] + red[3] + sb[0], 0.0f);
    }
}

// ---------------------------------------------------------------------------
// canon_all: eff[row,l] = tw if token l is the unique argmax for its id in the
// row (ties -> lowest index) and id not in {0,1,2,3}.  One grid for q and p:
// blocks [0,8) = q rows (L=128); blocks [8,136) = p rows x 2 chunks (L=512).
// ---------------------------------------------------------------------------
__global__ void canon_all(const int* __restrict__ q_ids, const int* __restrict__ p_ids,
                          const float* __restrict__ tw,
                          float* __restrict__ eff_q, float* __restrict__ eff_p)
{
    __shared__ int   sid[512];
    __shared__ float stw[512];
    int b = blockIdx.x, t = threadIdx.x;
    const int* ids; const float* twr; float* eff; int L, chunk;
    if (b < 8) {
        L = 128; chunk = 0;
        ids = q_ids + b * 128; twr = tw + b * 128; eff = eff_q + b * 128;
    } else {
        int pr = (b - 8) >> 1; chunk = (b - 8) & 1; L = 512;
        ids = p_ids + pr * 512; twr = tw + 1024 + pr * 512; eff = eff_p + pr * 512;
    }
    for (int l = t; l < L; l += 256) { sid[l] = ids[l]; stw[l] = twr[l]; }
    __syncthreads();
    int l = chunk * 256 + t;
    if (l < L) {
        int id = sid[l];
        float wv = stw[l];
        bool kill = (id < 4);  // UNUSED ids {0,1,2,3} -> zero
        #pragma unroll 8
        for (int m = 0; m < L; ++m) {
            int idm = sid[m];
            float wm = stw[m];
            bool beats = (idm == id) & (m != l) & ((wm > wv) | ((wm == wv) & (m < l)));
            kill = kill | beats;
        }
        eff[l] = kill ? 0.0f : wv;
    }
}

// ---------------------------------------------------------------------------
// 128x128xK bf16 MFMA GEMM, B^T layout:  C[m,n] = sum_k A[m,k]*B[n,k]
// tile 128x128, BK=64, 256 thr (4 waves, 2x2).
// MODE 0 (projection): C_bf16 = result + bias[n]; atomicAdd normsq[row].
//         grid x = row tile (mTiles) PLUS 64 tail x-tiles whose 512 blocks
//         compute the dense + sparse scores (inputs ready before launch).
// MODE 1 (maxsim): scale col j by pfac_j = pm/max(||v_j||*pm,eps), exclude
//         CLS cols (col%512==0), row-max -> atomicMax Mbuf[row*64+pb].
//         grid: x = col tile, y = row tile.
// Staging XOR swizzle (verified R4): lane l loads row r=l>>2, k-chunk
// c=(l&3)^((l>>3)&3); global stays 64B-segment coalesced, LDS fragment
// reads conflict-free at fragOff = (m16*4 + (quad^((m16>>1)&3)))*8.
// ---------------------------------------------------------------------------
template<int MODE>
__global__ __launch_bounds__(256, 2)
void gemm_bt(const unsigned short* __restrict__ A,
             const unsigned short* __restrict__ B,
             const float* __restrict__ bias,
             unsigned short* __restrict__ C,
             unsigned* __restrict__ Mbuf,
             float* __restrict__ normsq,
             const float* __restrict__ p_mask,
             int mTiles, int N, int K,
             // tail-block (dense+sparse) inputs, MODE 0 only:
             const float* __restrict__ qh, const float* __restrict__ ph,
             const int* __restrict__ q_ids, const int* __restrict__ p_ids,
             const float* __restrict__ eff_q, const float* __restrict__ eff_p,
             float* __restrict__ out)
{
    __shared__ unsigned short smA[128 * 64];
    __shared__ unsigned short smB[128 * 64];
    const int tid  = threadIdx.x;

    if (MODE == 0 && (int)blockIdx.x >= mTiles) {
        // ---- dense + sparse tail block ----
        int pair = ((int)blockIdx.x - mTiles) * 8 + (int)blockIdx.y;  // [0,512)
        int qb = pair >> 6, pb = pair & 63;
        char* lds = (char*)smA;
        int*   qid = (int*)lds;                 // 512 B
        float* qef = (float*)(lds + 512);       // 512 B
        int*   pid = (int*)(lds + 1024);        // 2 KB
        float* pef = (float*)(lds + 3072);      // 2 KB
        float* redD = (float*)(lds + 5120);     // 12 floats
        float* redS = (float*)(lds + 5184);     // 4 floats
        int t = tid;
        if (t < 128) { qid[t] = q_ids[qb * 128 + t]; qef[t] = eff_q[qb * 128 + t]; }
        for (int m = t; m < 512; m += 256) { pid[m] = p_ids[pb * 512 + m]; pef[m] = eff_p[pb * 512 + m]; }
        // dense partial (CLS rows)
        const float4* q4 = (const float4*)(qh + (size_t)qb * 128 * 1024);
        const float4* p4 = (const float4*)(ph + (size_t)pb * 512 * 1024);
        float4 a = q4[t], b = p4[t];
        float dot = a.x * b.x + a.y * b.y + a.z * b.z + a.w * b.w;
        float nq  = a.x * a.x + a.y * a.y + a.z * a.z + a.w * a.w;
        float np  = b.x * b.x + b.y * b.y + b.z * b.z + b.w * b.w;
        #pragma unroll
        for (int sh = 32; sh; sh >>= 1) {
            dot += __shfl_down(dot, sh, 64);
            nq  += __shfl_down(nq, sh, 64);
            np  += __shfl_down(np, sh, 64);
        }
        if ((t & 63) == 0) { int w = t >> 6; redD[w] = dot; redD[4 + w] = nq; redD[8 + w] = np; }
        __syncthreads();
        if (t == 0) {
            float d = redD[0] + redD[1] + redD[2] + redD[3];
            float n1 = redD[4] + redD[5] + redD[6] + redD[7];
            float n2 = redD[8] + redD[9] + redD[10] + redD[11];
            out[qb * 64 + pb] = d / (fmaxf(sqrtf(n1), 1e-12f) * fmaxf(sqrtf(n2), 1e-12f)) / TEMP;
        }
        // sparse: sum over matching ids
        float s = 0.0f;
        for (int idx = t; idx < 128 * 512; idx += 256) {
            int l = idx >> 9, m = idx & 511;
            if (qid[l] == pid[m]) s += qef[l] * pef[m];
        }
        #pragma unroll
        for (int sh = 32; sh; sh >>= 1) s += __shfl_down(s, sh, 64);
        if ((t & 63) == 0) redS[t >> 6] = s;
        __syncthreads();
        if (t == 0) out[512 + qb * 64 + pb] = (redS[0] + redS[1] + redS[2] + redS[3]) / TEMP;
        return;
    }

    const int lane = tid & 63;
    const int w    = tid >> 6;
    const int wm   = w >> 1, wn = w & 1;
    const int quad = lane >> 4, m16 = lane & 15;
    const int rowTile = (MODE == 0) ? blockIdx.x : blockIdx.y;
    const int colTile = (MODE == 0) ? blockIdx.y : blockIdx.x;
    const int rowBase = rowTile * 128;
    const int colBase = colTile * 128;

    // staging lane decomposition (XOR swizzle)
    const int sr = lane >> 2;
    const int scg = (lane & 3) ^ ((lane >> 3) & 3);
    const unsigned short* aG0 = A + (long long)(rowBase + w * 16 + sr) * K + scg * 8;
    const unsigned short* aG1 = aG0 + 64LL * K;
    const unsigned short* bG0 = B + (long long)(colBase + w * 16 + sr) * K + scg * 8;
    const unsigned short* bG1 = bG0 + 64LL * K;
    unsigned short* lA0 = smA + w * 512;          // khalf 0 at +0, khalf 1 at +4096
    unsigned short* lA1 = smA + (w + 4) * 512;
    unsigned short* lB0 = smB + w * 512;
    unsigned short* lB1 = smB + (w + 4) * 512;

    const int fragOff = (m16 * 4 + (quad ^ ((m16 >> 1) & 3))) * 8;

    floatx4 acc[4][4] = {};

    for (int k0 = 0; k0 < K; k0 += 64) {
        async_load16(lA0,        aG0 + k0);
        async_load16(lA0 + 4096, aG0 + k0 + 32);
        async_load16(lA1,        aG1 + k0);
        async_load16(lA1 + 4096, aG1 + k0 + 32);
        async_load16(lB0,        bG0 + k0);
        async_load16(lB0 + 4096, bG0 + k0 + 32);
        async_load16(lB1,        bG1 + k0);
        async_load16(lB1 + 4096, bG1 + k0 + 32);
        __syncthreads();
        #pragma unroll
        for (int h = 0; h < 2; ++h) {
            bf16x8 af[4], bfr[4];
            #pragma unroll
            for (int f = 0; f < 4; ++f) {
                af[f]  = *(const bf16x8*)(smA + h * 4096 + (wm * 4 + f) * 512 + fragOff);
                bfr[f] = *(const bf16x8*)(smB + h * 4096 + (wn * 4 + f) * 512 + fragOff);
            }
            #pragma unroll
            for (int i = 0; i < 4; ++i)
                #pragma unroll
                for (int j = 0; j < 4; ++j)
                    acc[i][j] = __builtin_amdgcn_mfma_f32_16x16x32_bf16(af[i], bfr[j], acc[i][j], 0, 0, 0);
        }
        __syncthreads();
    }

    if (MODE == 0) {
        float bcol[4];
        #pragma unroll
        for (int j = 0; j < 4; ++j) bcol[j] = bias[colBase + wn * 64 + j * 16 + m16];
        #pragma unroll
        for (int i = 0; i < 4; ++i) {
            int row0 = rowBase + wm * 64 + i * 16 + quad * 4;
            #pragma unroll
            for (int r = 0; r < 4; ++r) {
                float sq = 0.0f;
                #pragma unroll
                for (int j = 0; j < 4; ++j) {
                    int col = colBase + wn * 64 + j * 16 + m16;
                    float val = acc[i][j][r] + bcol[j];
                    C[(long long)(row0 + r) * N + col] = f2bf(val);
                    sq += val * val;
                }
                #pragma unroll
                for (int s = 1; s < 16; s <<= 1) sq += __shfl_xor(sq, s, 64);
                if (m16 == 0) atomicAdd(&normsq[row0 + r], sq);
            }
        }
    } else {
        const int pb = colBase >> 9;  // 512 p-tokens per passage
        float pfac[4];
        #pragma unroll
        for (int j = 0; j < 4; ++j) {
            int colg = colBase + wn * 64 + j * 16 + m16;
            float pm = p_mask[colg];
            float pn = sqrtf(normsq[1024 + colg]);
            pfac[j] = pm / fmaxf(pn * pm, 1e-12f);
        }
        #pragma unroll
        for (int i = 0; i < 4; ++i) {
            #pragma unroll
            for (int r = 0; r < 4; ++r) {
                float mx = -3.0e38f;
                #pragma unroll
                for (int j = 0; j < 4; ++j) {
                    int colg = colBase + wn * 64 + j * 16 + m16;
                    float v = acc[i][j][r] * pfac[j];
                    if ((colg & 511) == 0) v = -3.0e38f;  // exclude CLS column
                    mx = fmaxf(mx, v);
                }
                #pragma unroll
                for (int s = 1; s < 16; s <<= 1) mx = fmaxf(mx, __shfl_xor(mx, s, 64));
                if (m16 == 0) {
                    int row = rowBase + wm * 64 + i * 16 + quad * 4 + r;
                    atomicMax(&Mbuf[row * 64 + pb], encf(mx));
                }
            }
        }
    }
}

// ---------------------------------------------------------------------------
// colbert final reduce: out = sum_{i>=1} dec(M[i,pb])*qfac_i / msum / TEMP
// qfac_i = qm/max(||v_i||*qm, eps)  (deferred per-row normalization)
// ---------------------------------------------------------------------------
__global__ void colbert_reduce_k(const unsigned* __restrict__ Mbuf,
                                 const float* __restrict__ q_mask,
                                 const float* __restrict__ normsq,
                                 float* __restrict__ out)
{
    int pair = blockIdx.x * 4 + (threadIdx.x >> 6);
    int lane = threadIdx.x & 63;
    int qb = pair >> 6, pb = pair & 63;
    float s = 0.0f, msum = 0.0f;
    for (int i = 1 + lane; i < 128; i += 64) {
        float qm = q_mask[qb * 128 + i];
        float qn = sqrtf(normsq[qb * 128 + i]);
        float qfac = qm / fmaxf(qn * qm, 1e-12f);
        s += decf(Mbuf[(qb * 128 + i) * 64 + pb]) * qfac;
        msum += qm;
    }
    #pragma unroll
    for (int sh = 32; sh; sh >>= 1) {
        s += __shfl_down(s, sh, 64);
        msum += __shfl_down(msum, sh, 64);
    }
    if (lane == 0) out[1024 + qb * 64 + pb] = s / msum / TEMP;
}

// ---------------------------------------------------------------------------
extern "C" void kernel_launch(void* const* d_in, const int* in_sizes, int n_in,
                              void* d_out, int out_size, void* d_ws, size_t ws_size,
                              hipStream_t stream)
{
    const float* q_hidden = (const float*)d_in[0];   // [8,128,1024]
    const float* p_hidden = (const float*)d_in[1];   // [64,512,1024]
    const float* q_mask   = (const float*)d_in[2];   // [8,128]
    const float* p_mask   = (const float*)d_in[3];   // [64,512]
    const int*   q_ids    = (const int*)d_in[4];     // [8,128]
    const int*   p_ids    = (const int*)d_in[5];     // [64,512]
    const float* colbert_w = (const float*)d_in[6];  // [1024,1024]
    const float* colbert_b = (const float*)d_in[7];  // [1024]
    const float* sparse_w  = (const float*)d_in[8];  // [1024]
    const float* sparse_b  = (const float*)d_in[9];  // [1]
    float* out = (float*)d_out;                      // [3*512]

    // workspace carve-up (~135 MB). qhb|phb|Wb contiguous; qv|pv contiguous;
    // Mbuf|normsq contiguous (zeroed inside conv_zero_tw).
    char* ws = (char*)d_ws;
    size_t off = 0;
    auto carve = [&](size_t bytes) { char* p = ws + off; off += (bytes + 255) & ~(size_t)255; return p; };
    unsigned short* qhb  = (unsigned short*)carve((size_t)1024 * 1024 * 2);
    unsigned short* phb  = (unsigned short*)carve((size_t)32768 * 1024 * 2);
    unsigned short* Wb   = (unsigned short*)carve((size_t)1024 * 1024 * 2);
    unsigned short* qv   = (unsigned short*)carve((size_t)1024 * 1024 * 2);
    unsigned short* pv   = (unsigned short*)carve((size_t)32768 * 1024 * 2);
    unsigned* Mbuf  = (unsigned*)carve((size_t)1024 * 64 * 4);        // 256 KB
    float*    normsq = (float*)carve((size_t)33792 * 4);              // 132 KB (adjacent)
    float*    tw    = (float*)carve((size_t)33792 * 4);
    float*    eff_q = (float*)carve(1024 * 4);
    float*    eff_p = (float*)carve(32768 * 4);
    (void)phb; (void)Wb; (void)pv;

    // 1. fused bf16 conversion (q,p,W) + token weights + zero Mbuf/normsq
    conv_zero_tw<<<17408, 256, 0, stream>>>(q_hidden, p_hidden, colbert_w, qhb,
                                            sparse_w, sparse_b, tw, Mbuf);

    // 2. sparse canonicalization (q + p in one grid)
    canon_all<<<136, 256, 0, stream>>>(q_ids, p_ids, tw, eff_q, eff_p);

    // 3. projection GEMM over concat(q,p) (264 row tiles) + 64 tail x-tiles
    //    (512 blocks) computing dense + sparse scores concurrently
    gemm_bt<0><<<dim3(264 + 64, 8), 256, 0, stream>>>(
        qhb, Wb, colbert_b, qv, nullptr, normsq, nullptr, 264, 1024, 1024,
        q_hidden, p_hidden, q_ids, p_ids, eff_q, eff_p, out);

    // 4. maxsim GEMM with fused per-col normalization + max epilogue
    gemm_bt<1><<<dim3(256, 8), 256, 0, stream>>>(
        qv, pv, nullptr, nullptr, Mbuf, normsq, p_mask, 8, 32768, 1024,
        nullptr, nullptr, nullptr, nullptr, nullptr, nullptr, nullptr);

    // 5. colbert final reduce (needs all maxsim blocks done)
    colbert_reduce_k<<<128, 256, 0, stream>>>(Mbuf, q_mask, normsq, out);
}